// Round 6
// baseline (122.550 us; speedup 1.0000x reference)
//
#include <hip/hip_runtime.h>

#define NFREQ   257
#define NFRAMES 3751
#define NS      480000
#define HOP     128
#define WIN     512

#define NB      32
#define XP_REAL 480512              // reflect-padded valid length
#define XPS     491904              // per-batch stride incl. zero slack to frame 3839
#define AROWS   320                 // freq rows padded to 5*64 (rows 256.. used only by nyq row 256)
#define AIMAG_B 327680              // byte offset of imag basis plane (320*512*2)

#define BN      128                 // frames per block
#define NFT     30                  // frame tiles (30*128 = 3840)
#define STEPS   32                  // 4 fq * 8 ks  (rows 0..255; Nyquist handled separately)
#define XW_B    33792               // x-window LDS alloc (33536 used)
#define AHALF   16384               // one A buffer: ar 8KB + ai 8KB

typedef __attribute__((ext_vector_type(8))) short short8;
typedef __attribute__((ext_vector_type(4))) float f32x4;

__device__ __forceinline__ short f2bf(float f) {
    __bf16 b = (__bf16)f;
    return __builtin_bit_cast(short, b);
}

__device__ __forceinline__ float bf2f(short s) {
    unsigned int u = ((unsigned int)(unsigned short)s) << 16;
    return __builtin_bit_cast(float, u);
}

__device__ __forceinline__ void gload_lds16(const void* g, void* l) {
    __builtin_amdgcn_global_load_lds(
        (const __attribute__((address_space(1))) void*)g,
        (__attribute__((address_space(3))) void*)l,
        16, 0, 0);
}

// ---- prep 1: reflect-pad + bf16-convert x into ws ----
__global__ __launch_bounds__(256)
void prep_x(const float* __restrict__ x, short* __restrict__ xp) {
    int g = blockIdx.x * 256 + threadIdx.x;          // one 8-elem group
    int b = g / 61488;                               // XPS/8 groups per batch
    if (b >= NB) return;
    int i8 = (g - b * 61488) * 8;
    const float* __restrict__ xb = x + (size_t)b * NS;
    short8 v;
    int ix = i8 - 256;
    if (ix >= 0 && ix + 8 <= NS && i8 + 8 <= XP_REAL) {
        const float4* p = reinterpret_cast<const float4*>(xb + ix);
        float4 a0 = p[0], a1 = p[1];
        v[0]=f2bf(a0.x); v[1]=f2bf(a0.y); v[2]=f2bf(a0.z); v[3]=f2bf(a0.w);
        v[4]=f2bf(a1.x); v[5]=f2bf(a1.y); v[6]=f2bf(a1.z); v[7]=f2bf(a1.w);
    } else if (i8 >= XP_REAL) {
        #pragma unroll
        for (int j = 0; j < 8; ++j) v[j] = 0;        // zero slack (frames > 3750)
    } else {
        #pragma unroll
        for (int j = 0; j < 8; ++j) {
            int idx = ix + j;
            idx = idx < 0 ? -idx : idx;
            idx = idx >= NS ? 2 * NS - 2 - idx : idx;
            v[j] = f2bf(xb[idx]);
        }
    }
    *reinterpret_cast<short8*>(xp + (size_t)b * XPS + i8) = v;
}

// ---- prep 2: bf16 basis, rows padded to 320 ----
__global__ __launch_bounds__(256)
void prep_basis(const float* __restrict__ basis, short* __restrict__ ab) {
    int g = blockIdx.x * 256 + threadIdx.x;          // 2*320*512/8 = 40960 groups
    if (g >= 40960) return;
    int ri  = g / 20480;
    int rem = g - ri * 20480;
    int r   = rem >> 6;
    int k   = (rem & 63) * 8;
    short8 v;
    if (r < NFREQ) {
        const float4* p = reinterpret_cast<const float4*>(basis + ((size_t)(ri * NFREQ + r)) * WIN + k);
        float4 a0 = p[0], a1 = p[1];
        v[0]=f2bf(a0.x); v[1]=f2bf(a0.y); v[2]=f2bf(a0.z); v[3]=f2bf(a0.w);
        v[4]=f2bf(a1.x); v[5]=f2bf(a1.y); v[6]=f2bf(a1.z); v[7]=f2bf(a1.w);
    } else {
        #pragma unroll
        for (int j = 0; j < 8; ++j) v[j] = 0;
    }
    *reinterpret_cast<short8*>(ab + ((size_t)ri * AROWS + r) * WIN + k) = v;
}

// ---- Nyquist bin (f=256): basis real row = (-1)^t * w[t], imag = ~0 ----
__global__ __launch_bounds__(256)
void nyq_kernel(const short* __restrict__ xp,
                const short* __restrict__ ab,
                float* __restrict__ out)
{
    __shared__ float w[WIN];
    const int tid = threadIdx.x;
    const int b   = blockIdx.y;
    // weights: bf16 basis real-plane row 256
    w[tid]       = bf2f(ab[256 * WIN + tid]);
    w[tid + 256] = bf2f(ab[256 * WIN + tid + 256]);
    __syncthreads();
    int t = blockIdx.x * 256 + tid;
    if (t >= NFRAMES) return;
    const short* __restrict__ xrow = xp + (size_t)b * XPS + (size_t)t * HOP;
    float acc = 0.f;
    #pragma unroll
    for (int k = 0; k < WIN; k += 8) {
        short8 v = *reinterpret_cast<const short8*>(xrow + k);
        #pragma unroll
        for (int j = 0; j < 8; ++j)
            acc = fmaf(bf2f(v[j]), w[k + j], acc);
    }
    out[((size_t)b * NFREQ + 256) * NFRAMES + t] = fabsf(acc);
}

// ---- main: x-window staged once; 1-barrier/step double-buffered A pipeline ----
__global__ __launch_bounds__(256, 2)
void stft_mfma_kernel(const short* __restrict__ xp,
                      const short* __restrict__ ab,
                      float* __restrict__ out)
{
    __shared__ __align__(16) char smem[XW_B + 2 * AHALF];   // 66560 B -> 2 blocks/CU
    char* const xw   = smem;
    char* const aBuf = smem + XW_B;

    const int tid  = threadIdx.x;
    const int wave = tid >> 6;
    const int lane = tid & 63;
    const int wr   = wave >> 1;          // wave freq row (0..1)
    const int wc   = wave & 1;           // wave frame col (0..1)
    const int lgrp = lane >> 4;
    const int l15  = lane & 15;

    // bijective XCD chunk swizzle: 960 = 8 * 120
    const int logical = (blockIdx.x & 7) * 120 + (blockIdx.x >> 3);
    const int ft = logical % NFT;
    const int b  = logical / NFT;
    const int t0 = ft * BN;

    const char* abG = (const char*)ab;
    const int cbs = 16 * ((lane & 7) ^ (lane >> 3));   // per-lane A source swizzle

    // ---- prologue: issue x-window (once) + A stage for s=0; waits happen in-loop ----
    const char* xwg = (const char*)(xp + (size_t)b * XPS) + (size_t)t0 * 256;
    #pragma unroll
    for (int i = 0; i < 9; ++i) {
        int c = i * 4 + wave;
        if (c < 33) {
            int off = c * 1024 + lane * 16;
            int src = off ^ (((off >> 8) & 7) << 4);
            gload_lds16(xwg + src, xw + c * 1024);
        }
    }
    #pragma unroll
    for (int i = 0; i < 4; ++i) {
        int c = wave * 4 + i;                        // 0..15
        int r = (c & 7) * 8 + (lane >> 3);           // row 0..63
        const char* src = abG + (c < 8 ? 0 : AIMAG_B) + (size_t)r * 1024 + cbs;
        gload_lds16(src, aBuf + (c < 8 ? 0 : 8192) + (c & 7) * 1024);
    }

    f32x4 accR[2][4], accI[2][4];
    #pragma unroll
    for (int m = 0; m < 2; ++m)
        #pragma unroll
        for (int nt = 0; nt < 4; ++nt) {
            accR[m][nt] = f32x4{0.f, 0.f, 0.f, 0.f};
            accI[m][nt] = f32x4{0.f, 0.f, 0.f, 0.f};
        }

    #pragma unroll 1
    for (int s = 0; s < STEPS; ++s) {
        // my stage(s) loads (issued last iter / prologue) landed; then all waves' did
        asm volatile("s_waitcnt vmcnt(0)" ::: "memory");
        __builtin_amdgcn_sched_barrier(0);
        __syncthreads();
        __builtin_amdgcn_sched_barrier(0);

        char* const aCur = aBuf + (s & 1) * AHALF;

        // ---- issue NEXT A stage into the other buffer (overlaps compute below) ----
        if (s + 1 < STEPS) {
            char* const aNxt = aBuf + ((s + 1) & 1) * AHALF;
            const int fq  = (s + 1) >> 3;
            const int ksb = ((s + 1) & 7) * 128;
            #pragma unroll
            for (int i = 0; i < 4; ++i) {
                int c = wave * 4 + i;
                int r = (c & 7) * 8 + (lane >> 3);
                const char* src = abG + (c < 8 ? 0 : AIMAG_B)
                                + (size_t)(fq * 64 + r) * 1024 + ksb + cbs;
                gload_lds16(src, aNxt + (c < 8 ? 0 : 8192) + (c & 7) * 1024);
            }
        }
        __builtin_amdgcn_sched_barrier(0);   // pin: stage issue precedes compute

        // ---- compute current step from aCur ----
        const int ksb2 = (s & 7) * 128;
        #pragma unroll
        for (int ko = 0; ko < 2; ++ko) {
            const int kb = ko * 64 + lgrp * 16;
            short8 aRv[2], aIv[2], xv[4];
            #pragma unroll
            for (int m = 0; m < 2; ++m) {
                int row = wr * 32 + m * 16 + l15;
                int o = row * 128 + (kb ^ ((row & 7) << 4));
                aRv[m] = *reinterpret_cast<const short8*>(aCur + o);
                aIv[m] = *reinterpret_cast<const short8*>(aCur + 8192 + o);
            }
            #pragma unroll
            for (int nt = 0; nt < 4; ++nt) {
                int tl = wc * 64 + nt * 16 + l15;
                int flat = tl * 256 + ksb2 + ko * 64 + lgrp * 16;
                xv[nt] = *reinterpret_cast<const short8*>(xw + (flat ^ (((flat >> 8) & 7) << 4)));
            }
            #pragma unroll
            for (int m = 0; m < 2; ++m)
                #pragma unroll
                for (int nt = 0; nt < 4; ++nt) {
                    accR[m][nt] = __builtin_amdgcn_mfma_f32_16x16x32_bf16(aRv[m], xv[nt], accR[m][nt], 0, 0, 0);
                    accI[m][nt] = __builtin_amdgcn_mfma_f32_16x16x32_bf16(aIv[m], xv[nt], accI[m][nt], 0, 0, 0);
                }
        }

        // ---- per-freq-tile epilogue (after ks=7 of each fq); f = 0..255 < NFREQ ----
        if ((s & 7) == 7) {
            const int fq = s >> 3;
            const int fBase = fq * 64 + wr * 32 + lgrp * 4;
            const int tBase = t0 + wc * 64 + l15;
            float* ob = out + (size_t)b * NFREQ * NFRAMES;
            #pragma unroll
            for (int m = 0; m < 2; ++m)
                #pragma unroll
                for (int nt = 0; nt < 4; ++nt) {
                    int t = tBase + nt * 16;
                    if (t < NFRAMES) {
                        #pragma unroll
                        for (int r = 0; r < 4; ++r) {
                            int f = fBase + m * 16 + r;
                            float vr = accR[m][nt][r], vi = accI[m][nt][r];
                            ob[(size_t)f * NFRAMES + t] = sqrtf(vr * vr + vi * vi);
                        }
                    }
                    accR[m][nt] = f32x4{0.f, 0.f, 0.f, 0.f};
                    accI[m][nt] = f32x4{0.f, 0.f, 0.f, 0.f};
                }
        }
    }
}

extern "C" void kernel_launch(void* const* d_in, const int* in_sizes, int n_in,
                              void* d_out, int out_size, void* d_ws, size_t ws_size,
                              hipStream_t stream) {
    const float* x     = (const float*)d_in[0];
    const float* basis = (const float*)d_in[1];
    float* out = (float*)d_out;

    short* xp = (short*)d_ws;                         // 32*491904 bf16
    short* ab = xp + (size_t)NB * XPS;                // 2*320*512 bf16

    prep_x<<<dim3((NB * (XPS / 8) + 255) / 256), 256, 0, stream>>>(x, xp);
    prep_basis<<<dim3(160), 256, 0, stream>>>(basis, ab);

    stft_mfma_kernel<<<dim3(NFT * NB), 256, 0, stream>>>(xp, ab, out);  // 960 blocks
    nyq_kernel<<<dim3((NFRAMES + 255) / 256, NB), 256, 0, stream>>>(xp, ab, out);
}

// Round 7
// 88.499 us; speedup vs baseline: 1.3848x; 1.3848x over previous
//
#include <hip/hip_runtime.h>

#define NFREQ   257
#define NFRAMES 3751
#define NS      480000
#define HOP     128
#define WIN     512

#define NB      32
#define BN      128                 // frames per block
#define NFT     30                  // frame tiles (30*128 = 3840)
#define STEPS   32                  // 4 fq * 8 ks (rows 0..255; Nyquist in tail)

#define XWPITCH 272                 // padded row stride (128 samples + 16B pad)
#define XWROWS  131
#define XW_B    35632               // 131*272, 16B-multiple
#define AHALF   16384               // one A buffer: ar 8KB + ai 8KB
#define WNYQ_B  1024

typedef __attribute__((ext_vector_type(8))) short short8;
typedef __attribute__((ext_vector_type(4))) float f32x4;

__device__ __forceinline__ short f2bf(float f) {
    __bf16 b = (__bf16)f;
    return __builtin_bit_cast(short, b);
}

__device__ __forceinline__ float bf2f(short s) {
    unsigned int u = ((unsigned int)(unsigned short)s) << 16;
    return __builtin_bit_cast(float, u);
}

__device__ __forceinline__ void gload_lds16(const void* g, void* l) {
    __builtin_amdgcn_global_load_lds(
        (const __attribute__((address_space(1))) void*)g,
        (__attribute__((address_space(3))) void*)l,
        16, 0, 0);
}

// ---- prep: bake the per-step A staging stream (swizzle included) + nyq row ----
// abL layout: 32 steps x 16KB; step s chunk c byte (lane*16+j) holds
// basis[plane(c), fr=(s>>3)*64+(c&7)*8+(lane>>3)] element
// kel = ((s&7)*128 + 16*((lane&7)^(r&7)))/2 + j/2   (bf16)
__global__ __launch_bounds__(256)
void prep_basis2(const float* __restrict__ basis,
                 short* __restrict__ abL, short* __restrict__ wnyqG) {
    int g = blockIdx.x * 256 + threadIdx.x;
    if (g < 32768) {
        int ob   = g * 16;
        int s    = ob >> 14;
        int rem  = ob & 16383;
        int c    = rem >> 10;
        int lane = (rem >> 4) & 63;
        int r    = (c & 7) * 8 + (lane >> 3);
        int plane = (c >> 3) & 1;
        int fr   = (s >> 3) * 64 + r;                       // 0..255
        int kel  = (((s & 7) * 128 + 16 * ((lane & 7) ^ (r & 7))) >> 1);
        const float4* p = reinterpret_cast<const float4*>(
            basis + ((size_t)(plane * NFREQ + fr)) * WIN + kel);
        float4 a0 = p[0], a1 = p[1];
        short8 v;
        v[0]=f2bf(a0.x); v[1]=f2bf(a0.y); v[2]=f2bf(a0.z); v[3]=f2bf(a0.w);
        v[4]=f2bf(a1.x); v[5]=f2bf(a1.y); v[6]=f2bf(a1.z); v[7]=f2bf(a1.w);
        *reinterpret_cast<short8*>(reinterpret_cast<char*>(abL) + ob) = v;
    } else if (g < 32832) {                                 // nyq row: real plane row 256
        int j = g - 32768;
        const float4* p = reinterpret_cast<const float4*>(
            basis + (size_t)256 * WIN + j * 8);
        float4 a0 = p[0], a1 = p[1];
        short8 v;
        v[0]=f2bf(a0.x); v[1]=f2bf(a0.y); v[2]=f2bf(a0.z); v[3]=f2bf(a0.w);
        v[4]=f2bf(a1.x); v[5]=f2bf(a1.y); v[6]=f2bf(a1.z); v[7]=f2bf(a1.w);
        *reinterpret_cast<short8*>(wnyqG + j * 8) = v;
    }
}

// ---- main: fp32 x window -> padded bf16 LDS (once); A dbuf pipeline; nyq tail ----
__global__ __launch_bounds__(256, 2)
void stft_mfma_kernel(const float* __restrict__ x,
                      const short* __restrict__ abL,
                      const short* __restrict__ wnyqG,
                      float* __restrict__ out)
{
    __shared__ __align__(16) char smem[XW_B + 2 * AHALF + WNYQ_B];  // 69424 B
    char* const xw   = smem;
    char* const aBuf = smem + XW_B;
    char* const wnyq = smem + XW_B + 2 * AHALF;

    const int tid  = threadIdx.x;
    const int wave = tid >> 6;
    const int lane = tid & 63;
    const int wr   = wave >> 1;          // wave freq row (0..1)
    const int wc   = wave & 1;           // wave frame col (0..1)
    const int lgrp = lane >> 4;
    const int l15  = lane & 15;

    // bijective XCD chunk swizzle: 960 = 8 * 120
    const int logical = (blockIdx.x & 7) * 120 + (blockIdx.x >> 3);
    const int ft = logical % NFT;
    const int b  = logical / NFT;
    const int t0 = ft * BN;

    const char* abLc = (const char*)abL;

    // ---- prologue A: issue step-0 stage + nyq weights (gload_lds) ----
    #pragma unroll
    for (int i = 0; i < 4; ++i) {
        int c = wave * 4 + i;
        gload_lds16(abLc + c * 1024 + lane * 16,
                    aBuf + ((c & 8) ? 8192 : 0) + (c & 7) * 1024);
    }
    if (wave == 0)
        gload_lds16((const char*)wnyqG + lane * 16, wnyq);

    // ---- prologue X: fp32 window -> bf16, padded rows, reflect at edges ----
    {
        const float* __restrict__ xb = x + (size_t)b * NS;
        const int sbase = t0 * 128 - 256;          // unpadded index of window sample 0
        #pragma unroll
        for (int i = 0; i < 9; ++i) {
            int g = tid + i * 256;                 // 16B (8-sample) group
            if (g < 2096) {
                int ix = sbase + g * 8;
                short8 v;
                if (ix >= 0 && ix + 8 <= NS) {     // interior fast path
                    const float4* p = reinterpret_cast<const float4*>(xb + ix);
                    float4 a0 = p[0], a1 = p[1];
                    v[0]=f2bf(a0.x); v[1]=f2bf(a0.y); v[2]=f2bf(a0.z); v[3]=f2bf(a0.w);
                    v[4]=f2bf(a1.x); v[5]=f2bf(a1.y); v[6]=f2bf(a1.z); v[7]=f2bf(a1.w);
                } else {
                    #pragma unroll
                    for (int q = 0; q < 8; ++q) {
                        int idx = ix + q;
                        if (idx < 0) idx = -idx;
                        if (idx >= NS + 256) { v[q] = 0; continue; }  // zero slack
                        if (idx >= NS) idx = 2 * NS - 2 - idx;        // reflect
                        v[q] = f2bf(xb[idx]);
                    }
                }
                *reinterpret_cast<short8*>(xw + (g >> 4) * XWPITCH + (g & 15) * 16) = v;
            }
        }
    }

    f32x4 accR[2][4], accI[2][4];
    #pragma unroll
    for (int m = 0; m < 2; ++m)
        #pragma unroll
        for (int nt = 0; nt < 4; ++nt) {
            accR[m][nt] = f32x4{0.f, 0.f, 0.f, 0.f};
            accI[m][nt] = f32x4{0.f, 0.f, 0.f, 0.f};
        }

    // hoisted X row bases: (wc*64 + nt*16 + l15) * 272
    const int tlb = (wc * 64 + l15) * XWPITCH;

    #pragma unroll 1
    for (int s = 0; s < STEPS; ++s) {
        // stage(s) loads landed; all waves' ds_writes + loads visible after barrier
        asm volatile("s_waitcnt vmcnt(0)" ::: "memory");
        __builtin_amdgcn_sched_barrier(0);
        __syncthreads();
        __builtin_amdgcn_sched_barrier(0);

        char* const aCur = aBuf + (s & 1) * AHALF;

        // ---- issue NEXT A stage (uniform base + lane*16; overlaps compute) ----
        if (s + 1 < STEPS) {
            char* const aNxt = aBuf + ((s + 1) & 1) * AHALF;
            const char* sb = abLc + (size_t)(s + 1) * 16384;
            #pragma unroll
            for (int i = 0; i < 4; ++i) {
                int c = wave * 4 + i;
                gload_lds16(sb + c * 1024 + lane * 16,
                            aNxt + ((c & 8) ? 8192 : 0) + (c & 7) * 1024);
            }
        }
        __builtin_amdgcn_sched_barrier(0);   // pin: stage issue precedes compute

        // ---- compute current step ----
        const int ksb2 = (s & 7) * 128;
        #pragma unroll
        for (int ko = 0; ko < 2; ++ko) {
            const int kb = ko * 64 + lgrp * 16;
            short8 aRv[2], aIv[2], xv[4];
            #pragma unroll
            for (int m = 0; m < 2; ++m) {
                int row = wr * 32 + m * 16 + l15;
                int o = row * 128 + (kb ^ ((row & 7) << 4));
                aRv[m] = *reinterpret_cast<const short8*>(aCur + o);
                aIv[m] = *reinterpret_cast<const short8*>(aCur + 8192 + o);
            }
            {
                int r8 = ksb2 + kb;                      // 0..1008
                int T  = r8 + ((r8 >> 4) & 0x30);        // padded-row remap
                #pragma unroll
                for (int nt = 0; nt < 4; ++nt)
                    xv[nt] = *reinterpret_cast<const short8*>(xw + tlb + nt * (16 * XWPITCH) + T);
            }
            #pragma unroll
            for (int m = 0; m < 2; ++m)
                #pragma unroll
                for (int nt = 0; nt < 4; ++nt) {
                    accR[m][nt] = __builtin_amdgcn_mfma_f32_16x16x32_bf16(aRv[m], xv[nt], accR[m][nt], 0, 0, 0);
                    accI[m][nt] = __builtin_amdgcn_mfma_f32_16x16x32_bf16(aIv[m], xv[nt], accI[m][nt], 0, 0, 0);
                }
        }

        // ---- per-freq-tile epilogue (after ks=7 of each fq); f = 0..255 ----
        if ((s & 7) == 7) {
            const int fq = s >> 3;
            const int fBase = fq * 64 + wr * 32 + lgrp * 4;
            const int tBase = t0 + wc * 64 + l15;
            float* ob = out + (size_t)b * NFREQ * NFRAMES;
            #pragma unroll
            for (int m = 0; m < 2; ++m)
                #pragma unroll
                for (int nt = 0; nt < 4; ++nt) {
                    int t = tBase + nt * 16;
                    if (t < NFRAMES) {
                        #pragma unroll
                        for (int r = 0; r < 4; ++r) {
                            int f = fBase + m * 16 + r;
                            float vr = accR[m][nt][r], vi = accI[m][nt][r];
                            ob[(size_t)f * NFRAMES + t] = sqrtf(vr * vr + vi * vi);
                        }
                    }
                    accR[m][nt] = f32x4{0.f, 0.f, 0.f, 0.f};
                    accI[m][nt] = f32x4{0.f, 0.f, 0.f, 0.f};
                }
        }
    }

    // ---- Nyquist tail: f=256, |dot(x_frame, w)|; x & w already in LDS ----
    {
        const int fl = wave * 32 + (lane & 31);       // local frame 0..127
        const int h  = lane >> 5;                     // half of the 512-window
        const int xbase = (fl + 2 * h) * XWPITCH;
        const int wbase = h * 512;
        float acc = 0.f;
        #pragma unroll
        for (int j = 0; j < 32; ++j) {
            short8 xv8 = *reinterpret_cast<const short8*>(
                xw + xbase + (j >> 4) * XWPITCH + (j & 15) * 16);
            short8 wv8 = *reinterpret_cast<const short8*>(wnyq + wbase + j * 16);
            #pragma unroll
            for (int q = 0; q < 8; ++q)
                acc = fmaf(bf2f(xv8[q]), bf2f(wv8[q]), acc);
        }
        acc += __shfl_xor(acc, 32);
        int t = t0 + fl;
        if (h == 0 && t < NFRAMES)
            out[((size_t)b * NFREQ + 256) * NFRAMES + t] = fabsf(acc);
    }
}

extern "C" void kernel_launch(void* const* d_in, const int* in_sizes, int n_in,
                              void* d_out, int out_size, void* d_ws, size_t ws_size,
                              hipStream_t stream) {
    const float* x     = (const float*)d_in[0];
    const float* basis = (const float*)d_in[1];
    float* out = (float*)d_out;

    short* abL   = (short*)d_ws;                       // 32 steps x 16KB = 512KB
    short* wnyqG = abL + 262144;                       // 512 bf16

    prep_basis2<<<dim3(129), 256, 0, stream>>>(basis, abL, wnyqG);
    stft_mfma_kernel<<<dim3(NFT * NB), 256, 0, stream>>>(x, abL, wnyqG, out);  // 960 blocks
}